// Round 2
// baseline (5429.190 us; speedup 1.0000x reference)
//
#include <hip/hip_runtime.h>

typedef unsigned short ushort_t;
typedef _Float16 half_t;
typedef __attribute__((ext_vector_type(8))) _Float16 half8;
typedef __attribute__((ext_vector_type(4))) float f32x4;

#define B_ 256
#define T_ 200
#define X_ 128
#define H_ 512

// swizzled weight offsets in d_ws (f16 elements)
#define OFF_WO1 0
#define OFF_WO2 57344
#define OFF_WU1 122880
#define OFF_WR1 251904
#define OFF_WN1 380928
#define OFF_WU2 509952
#define OFF_WR2 575488
#define OFF_WN2 641024
#define OFF_WT1 772096
#define OFF_WT2 886784
#define OFF_WT3 901120
#define SWZ_TOTAL 1032192
#define DTS_BYTE_OFF (SWZ_TOTAL * 2)

#define LOG2E 1.4426950408889634f

// ===== r19: raise the real VGPR budget, retry deep unroll. Ledger: =====
//  r12/r14: unroll>4 / A-caching at the 64-VGPR cap -> spill. 
//  r15: split-K S1/S5 (+2 barriers) -> +8.5%. CLOSED (barriers dominate).
//  r16: x-part hoist via HBM epilogue -> +5%. CLOSED.
//  r18: launch_bounds(1024,4) did NOT raise the budget (VGPR_Count stayed 64)
//       -> unroll-8 spilled again (WRITE_SIZE 2944->11904 KB, dur 3651->5380).
//       The default amdgpu-waves-per-eu min=8 pins regs at 512/8=64.
//  r18a (kept): S6->S0 barrier removed (S6 reads tn/regs, S0 writes yc).
//  r18b (kept): x_{t+1} register prefetch, HBM latency hidden under S1..S6.
//  r19: __attribute__((amdgpu_waves_per_eu(4,4))): min 4 waves/EU = exactly
//       our real occupancy (1 block = 16 waves/CU) -> 128-VGPR budget, free.
//       gemm_tile unroll 8 under the new budget (8 B-frags in flight = 64
//       VGPR + ~2-ahead A-frags + state ~= 125 <= 128).
//  Tripwires: VGPR_Count must read >64 (attribute took) and WRITE_SIZE ~2.9MB
//       (no spill). VGPR=64 -> attribute failed, revert unroll. VGPR>64 but
//       WRITE_SIZE>5MB -> unroll 8 too fat, drop to 6.

struct Args {
  const float *x_data, *x_time;
  const float *Wu1, *bu1, *Wu2, *bu2;
  const float *Wr1, *br1, *Wr2, *br2;
  const float *Wn1, *bn1, *Wn2, *bn2;
  const float *Wo1, *bo1, *Wo2, *bo2;
  const float *Wt1, *bt1, *Wt2, *bt2, *Wt3, *bt3;
  float* out;      // f32 output: mu[256*512] then sigma[256*512]
  half_t* wsw;     // swizzled weights (f16)
  float* dts;      // 200 per-step dt values
};

// hw-instruction activations (validated r12/r13: VALU -70%, absmax unchanged)
__device__ __forceinline__ float fast_sigm(float x) {
  return __builtin_amdgcn_rcpf(1.0f + __builtin_amdgcn_exp2f(-LOG2E * x));
}
__device__ __forceinline__ float fast_tanh(float x) {
  return 1.0f - 2.0f * __builtin_amdgcn_rcpf(1.0f + __builtin_amdgcn_exp2f((2.0f * LOG2E) * x));
}

// One 16x16 output tile, K = KB*32. A from LDS, B from pre-swizzled global.
// unroll 8 under the 128-VGPR budget (amdgpu_waves_per_eu(4,4)); at the old
// 64-cap this spilled (r12/r18).
template <int KB>
__device__ __forceinline__ f32x4 gemm_tile(const half_t* __restrict__ wtile,
                                           const half_t* __restrict__ abase,
                                           int astride, int lane, f32x4 acc) {
  const half_t* ap = abase + (lane & 15) * astride + 8 * (lane >> 4);
  const half_t* wp = wtile + lane * 8;
#pragma unroll 8
  for (int kb = 0; kb < KB; ++kb) {
    half8 af = *(const half8*)(ap + kb * 32);
    half8 bf = *(const half8*)(wp + kb * 512);
    acc = __builtin_amdgcn_mfma_f32_16x16x32_f16(af, bf, acc, 0, 0, 0);
  }
  return acc;
}

// Pre-swizzle f32 weights into f16 MFMA B-fragment layout, K padded to mult of
// 32 (zeros), N padded to mult of 16 (zeros).
__global__ void swz_kernel(Args a) {
  struct WT { const float* src; int off; int KB; int Kr; int Nr; };
  const WT tbl[11] = {
      {a.Wo1, OFF_WO1, 16, 512, 100},  {a.Wo2, OFF_WO2, 4, 100, 512},
      {a.Wu1, OFF_WU1, 36, 1152, 100}, {a.Wr1, OFF_WR1, 36, 1152, 100},
      {a.Wn1, OFF_WN1, 36, 1152, 100}, {a.Wu2, OFF_WU2, 4, 100, 512},
      {a.Wr2, OFF_WR2, 4, 100, 512},   {a.Wn2, OFF_WN2, 4, 100, 1024},
      {a.Wt1, OFF_WT1, 32, 1024, 100}, {a.Wt2, OFF_WT2, 4, 100, 100},
      {a.Wt3, OFF_WT3, 4, 100, 1024}};
  const int ends[11] = {OFF_WO2, OFF_WU1, OFF_WR1, OFF_WN1, OFF_WU2, OFF_WR2,
                        OFF_WN2, OFF_WT1, OFF_WT2, OFF_WT3, SWZ_TOTAL};
  int gid = blockIdx.x * blockDim.x + threadIdx.x;
  int e8 = gid * 8;
  if (e8 >= SWZ_TOTAL) return;
  int w = 0;
  while (e8 >= ends[w]) ++w;
  const WT T = tbl[w];
  int local = e8 - T.off;
  int lane = (local >> 3) & 63;
  int blk = local >> 9;  // nt*KB + kb
  int kb = blk % T.KB, nt = blk / T.KB;
  int n = nt * 16 + (lane & 15);
  int k0 = kb * 32 + 8 * (lane >> 4);
#pragma unroll
  for (int j = 0; j < 8; ++j) {
    int k = k0 + j;
    float v = (k < T.Kr && n < T.Nr) ? T.src[k * T.Nr + n] : 0.0f;
    a.wsw[e8 + j] = (half_t)v;
  }
}

__global__ void dts_kernel(Args a) {
  int t = threadIdx.x;
  if (t >= T_) return;
  float v;
  if (t == 0)      v = -0.01f;
  else if (t == 1) v = a.x_time[T_ - 1] - a.x_time[0];
  else             v = a.x_time[t - 2] - a.x_time[t - 1];
  a.dts[t] = v;
}

// Persistent ODE-GRU scan: 16 blocks x 1024 threads; block b owns batch rows
// [16b,16b+16). State in registers at C-fragment positions:
//   hreg[s*4+i] = h[m=g*4+i][n=(wave+s*16)*16+lm]  (s=0,1)
// amdgpu_waves_per_eu(4,4): we run exactly 1 block/CU = 4 waves/SIMD; the
// backend default (min 8 waves/EU) pinned VGPRs at 64 and forced every
// deep-pipelining attempt to spill (r12/r14/r18). min=4 -> 128-VGPR budget.
__global__ __launch_bounds__(1024)
__attribute__((amdgpu_waves_per_eu(4, 4)))
void odegru_kernel(Args a) {
  // yc stride 1160 f16 (=580 dw == 4 mod 32 -> 2-way-free LDS banks)
  __shared__ __align__(16) half_t yc[16 * 1160];   // [h_ode | hs | x] then c
  __shared__ __align__(16) half_t tg[16 * 136];
  __shared__ __align__(16) half_t tu[16 * 136];
  __shared__ __align__(16) half_t tr[16 * 136];
  __shared__ __align__(16) half_t tn[16 * 136];
  __shared__ float dts_s[T_];

  const int tid = threadIdx.x;
  const int wave = tid >> 6;
  const int lane = tid & 63;
  const int lm = lane & 15;
  const int g = lane >> 4;
  const int row0 = blockIdx.x * 16;

  for (int i = tid; i < 16 * 136; i += 1024) {
    tg[i] = (half_t)0.f; tu[i] = (half_t)0.f; tr[i] = (half_t)0.f; tn[i] = (half_t)0.f;
  }
  if (tid < T_) dts_s[tid] = a.dts[tid];

  // x_t register prefetch: thread covers (xm, xk) and (xm+8, xk); 2048 elems.
  const int xm = tid >> 7, xk = tid & 127;
  const float* xb0 = a.x_data + (long)(row0 + xm) * T_ * X_ + xk;
  const float* xb1 = xb0 + (long)8 * T_ * X_;
  float xp0 = xb0[0];  // t = 0
  float xp1 = xb1[0];

  float hreg[8], hsreg[8];
#pragma unroll
  for (int i = 0; i < 8; ++i) { hreg[i] = 0.f; hsreg[i] = 0.f; }
  float ureg[8];  // u gate: producer wave == consumer wave
  __syncthreads();

  for (int t = 0; t < T_; ++t) {
    const float dt = dts_s[t];
    // ---- S0: yc = [f16(h) | f16(hs) | f16(x_t)] (merged with S6 tail:
    //          no barrier between S6 and S0 — S6 reads tn/regs, S0 writes yc)
#pragma unroll
    for (int s = 0; s < 2; ++s) {
      int n = (wave + s * 16) * 16 + lm;
#pragma unroll
      for (int i = 0; i < 4; ++i) {
        int m = g * 4 + i;
        yc[m * 1160 + n]       = (half_t)hreg[s * 4 + i];
        yc[m * 1160 + 512 + n] = (half_t)hsreg[s * 4 + i];
      }
    }
    yc[xm * 1160 + 1024 + xk]       = (half_t)xp0;
    yc[(xm + 8) * 1160 + 1024 + xk] = (half_t)xp1;
    // prefetch x_{t+1}: latency hides under S1..S6 of this step
    if (t + 1 < T_) {
      xp0 = xb0[(t + 1) * X_];
      xp1 = xb1[(t + 1) * X_];
    }
    __syncthreads();
    // ---- S1: tg = tanh(h @ Wo1 + bo1) ----
    for (int nt = wave; nt < 7; nt += 16) {
      f32x4 acc = {0.f, 0.f, 0.f, 0.f};
      acc = gemm_tile<16>(a.wsw + OFF_WO1 + nt * 16 * 512, yc, 1160, lane, acc);
      int n = nt * 16 + lm;
      if (n < 100) {
        float bias = a.bo1[n];
#pragma unroll
        for (int i = 0; i < 4; ++i)
          tg[(g * 4 + i) * 136 + n] = (half_t)fast_tanh(acc[i] + bias);
      }
    }
    __syncthreads();
    // ---- S2: h_ode = h + dt*(tg @ Wo2 + bo2); hreg := h_ode; yc := f16(h_ode) ----
#pragma unroll
    for (int s = 0; s < 2; ++s) {
      int nt = wave + s * 16;
      f32x4 acc = {0.f, 0.f, 0.f, 0.f};
      acc = gemm_tile<4>(a.wsw + OFF_WO2 + nt * 4 * 512, tg, 136, lane, acc);
      int n = nt * 16 + lm;
      float bias = a.bo2[n];
#pragma unroll
      for (int i = 0; i < 4; ++i) {
        int m = g * 4 + i;
        float h_ode = hreg[s * 4 + i] + dt * (acc[i] + bias);
        hreg[s * 4 + i] = h_ode;
        yc[m * 1160 + n] = (half_t)h_ode;
      }
    }
    __syncthreads();
    // ---- S3: tu = tanh(yc@Wu1+bu1), tr = tanh(yc@Wr1+br1) (14 tiles) ----
    for (int nt = wave; nt < 14; nt += 16) {
      bool isU = nt < 7;
      int nt7 = isU ? nt : nt - 7;
      f32x4 acc = {0.f, 0.f, 0.f, 0.f};
      acc = gemm_tile<36>(a.wsw + (isU ? OFF_WU1 : OFF_WR1) + nt7 * 36 * 512, yc, 1160, lane, acc);
      int n = nt7 * 16 + lm;
      if (n < 100) {
        float bias = (isU ? a.bu1 : a.br1)[n];
        half_t* dst = isU ? tu : tr;
#pragma unroll
        for (int i = 0; i < 4; ++i)
          dst[(g * 4 + i) * 136 + n] = (half_t)fast_tanh(acc[i] + bias);
      }
    }
    __syncthreads();
    // ---- S4: u -> ureg ; r -> fused c-build into yc ----
#pragma unroll
    for (int s = 0; s < 2; ++s) {
      int nt = wave + s * 16;
      f32x4 acc = {0.f, 0.f, 0.f, 0.f};
      acc = gemm_tile<4>(a.wsw + OFF_WU2 + nt * 4 * 512, tu, 136, lane, acc);
      int n = nt * 16 + lm;
      float bias = a.bu2[n];
#pragma unroll
      for (int i = 0; i < 4; ++i) ureg[s * 4 + i] = fast_sigm(acc[i] + bias);
    }
#pragma unroll
    for (int s = 0; s < 2; ++s) {
      int nt = wave + s * 16;
      f32x4 acc = {0.f, 0.f, 0.f, 0.f};
      acc = gemm_tile<4>(a.wsw + OFF_WR2 + nt * 4 * 512, tr, 136, lane, acc);
      int n = nt * 16 + lm;
      float bias = a.br2[n];
#pragma unroll
      for (int i = 0; i < 4; ++i) {
        int m = g * 4 + i;
        float r = fast_sigm(acc[i] + bias);
        yc[m * 1160 + n]       = (half_t)(hreg[s * 4 + i] * r);
        yc[m * 1160 + 512 + n] = (half_t)(hsreg[s * 4 + i] * r);
      }
    }
    __syncthreads();
    // ---- S5: tn = tanh(c @ Wn1 + bn1) ----
    for (int nt = wave; nt < 7; nt += 16) {
      f32x4 acc = {0.f, 0.f, 0.f, 0.f};
      acc = gemm_tile<36>(a.wsw + OFF_WN1 + nt * 36 * 512, yc, 1160, lane, acc);
      int n = nt * 16 + lm;
      if (n < 100) {
        float bias = a.bn1[n];
#pragma unroll
        for (int i = 0; i < 4; ++i)
          tn[(g * 4 + i) * 136 + n] = (half_t)fast_tanh(acc[i] + bias);
      }
    }
    __syncthreads();
    // ---- S6: ns = tn @ Wn2 + bn2; gated state update in registers ----
    //      (no trailing barrier: merged with next step's S0)
#pragma unroll
    for (int s = 0; s < 4; ++s) {
      int nt = wave + s * 16;
      f32x4 acc = {0.f, 0.f, 0.f, 0.f};
      acc = gemm_tile<4>(a.wsw + OFF_WN2 + nt * 4 * 512, tn, 136, lane, acc);
      int n = nt * 16 + lm;
      float bias = a.bn2[n];
      if (s < 2) {  // m-part -> h update
#pragma unroll
        for (int i = 0; i < 4; ++i) {
          float u = ureg[s * 4 + i];
          float mval = acc[i] + bias;
          hreg[s * 4 + i] = (1.0f - u) * mval + u * hreg[s * 4 + i];
        }
      } else {      // s-part -> hs update (same n-tile as ureg[s-2])
#pragma unroll
        for (int i = 0; i < 4; ++i) {
          float u = ureg[(s - 2) * 4 + i];
          float sval = fabsf(acc[i] + bias);
          hsreg[(s - 2) * 4 + i] = (1.0f - u) * sval + u * hsreg[(s - 2) * 4 + i];
        }
      }
    }
  }

  // ---- Final decoder ----
#pragma unroll
  for (int s = 0; s < 2; ++s) {
    int n = (wave + s * 16) * 16 + lm;
#pragma unroll
    for (int i = 0; i < 4; ++i) {
      int m = g * 4 + i;
      yc[m * 1160 + n]       = (half_t)hreg[s * 4 + i];
      yc[m * 1160 + 512 + n] = (half_t)hsreg[s * 4 + i];
    }
  }
  __syncthreads();
  for (int nt = wave; nt < 7; nt += 16) {  // z1 = tanh(hcat@Wt1+bt1)
    f32x4 acc = {0.f, 0.f, 0.f, 0.f};
    acc = gemm_tile<32>(a.wsw + OFF_WT1 + nt * 32 * 512, yc, 1160, lane, acc);
    int n = nt * 16 + lm;
    if (n < 100) {
      float bias = a.bt1[n];
#pragma unroll
      for (int i = 0; i < 4; ++i)
        tu[(g * 4 + i) * 136 + n] = (half_t)fast_tanh(acc[i] + bias);
    }
  }
  __syncthreads();
  for (int nt = wave; nt < 7; nt += 16) {  // z2 = tanh(z1@Wt2+bt2)
    f32x4 acc = {0.f, 0.f, 0.f, 0.f};
    acc = gemm_tile<4>(a.wsw + OFF_WT2 + nt * 4 * 512, tu, 136, lane, acc);
    int n = nt * 16 + lm;
    if (n < 100) {
      float bias = a.bt2[n];
#pragma unroll
      for (int i = 0; i < 4; ++i)
        tr[(g * 4 + i) * 136 + n] = (half_t)fast_tanh(acc[i] + bias);
    }
  }
  __syncthreads();
#pragma unroll
  for (int s = 0; s < 4; ++s) {  // z3 = z2@Wt3+bt3 -> mu | sigma (f32 out)
    int nt = wave + s * 16;
    f32x4 acc = {0.f, 0.f, 0.f, 0.f};
    acc = gemm_tile<4>(a.wsw + OFF_WT3 + nt * 4 * 512, tr, 136, lane, acc);
    int n = nt * 16 + lm;
    float bias = a.bt3[n];
#pragma unroll
    for (int i = 0; i < 4; ++i) {
      int grow = row0 + g * 4 + i;
      float val = acc[i] + bias;
      if (n < 512)
        a.out[(size_t)grow * 512 + n] = val;
      else
        a.out[(size_t)(B_ * 512) + (size_t)grow * 512 + (n - 512)] = fabsf(val);
    }
  }
}

extern "C" void kernel_launch(void* const* d_in, const int* in_sizes, int n_in,
                              void* d_out, int out_size, void* d_ws, size_t ws_size,
                              hipStream_t stream) {
  Args a;
  a.x_data = (const float*)d_in[0];
  a.x_time = (const float*)d_in[1];
  a.Wu1 = (const float*)d_in[2];  a.bu1 = (const float*)d_in[3];
  a.Wu2 = (const float*)d_in[4];  a.bu2 = (const float*)d_in[5];
  a.Wr1 = (const float*)d_in[6];  a.br1 = (const float*)d_in[7];
  a.Wr2 = (const float*)d_in[8];  a.br2 = (const float*)d_in[9];
  a.Wn1 = (const float*)d_in[10]; a.bn1 = (const float*)d_in[11];
  a.Wn2 = (const float*)d_in[12]; a.bn2 = (const float*)d_in[13];
  a.Wo1 = (const float*)d_in[14]; a.bo1 = (const float*)d_in[15];
  a.Wo2 = (const float*)d_in[16]; a.bo2 = (const float*)d_in[17];
  a.Wt1 = (const float*)d_in[18]; a.bt1 = (const float*)d_in[19];
  a.Wt2 = (const float*)d_in[20]; a.bt2 = (const float*)d_in[21];
  a.Wt3 = (const float*)d_in[22]; a.bt3 = (const float*)d_in[23];
  a.out = (float*)d_out;
  a.wsw = (half_t*)d_ws;
  a.dts = (float*)((char*)d_ws + DTS_BYTE_OFF);

  swz_kernel<<<dim3(504), dim3(256), 0, stream>>>(a);
  dts_kernel<<<dim3(1), dim3(256), 0, stream>>>(a);
  odegru_kernel<<<dim3(16), dim3(1024), 0, stream>>>(a);
}

// Round 3
// 5415.107 us; speedup vs baseline: 1.0026x; 1.0026x over previous
//
#include <hip/hip_runtime.h>

typedef unsigned short ushort_t;
typedef _Float16 half_t;
typedef __attribute__((ext_vector_type(8))) _Float16 half8;
typedef __attribute__((ext_vector_type(4))) float f32x4;

#define B_ 256
#define T_ 200
#define X_ 128
#define H_ 512

// swizzled weight offsets in d_ws (f16 elements)
#define OFF_WO1 0
#define OFF_WO2 57344
#define OFF_WU1 122880
#define OFF_WR1 251904
#define OFF_WN1 380928
#define OFF_WU2 509952
#define OFF_WR2 575488
#define OFF_WN2 641024
#define OFF_WT1 772096
#define OFF_WT2 886784
#define OFF_WT3 901120
#define SWZ_TOTAL 1032192
#define DTS_BYTE_OFF (SWZ_TOTAL * 2)

#define LOG2E 1.4426950408889634f

// ===== r20: break the 64-VGPR pin via LDS-implied occupancy. Ledger: =====
//  r12/r14: unroll>4 at 64-VGPR cap -> spill. r15: split-K -> +8.5%. CLOSED.
//  r16: x-part hoist -> +5%. CLOSED.
//  r18: launch_bounds(1024,4) didn't move VGPR budget -> spill, 5380us.
//  r19: amdgpu_waves_per_eu(4,4) changed SGPR (48->112) but NOT VGPR (64) ->
//       same spill, 5429us. Diagnosis: backend derives its occupancy target
//       from LDS-implied blocks/CU. LDS=55808B -> 2 blocks/CU fit -> target
//       8 waves/EU -> 64 VGPR, attribute ignored for VGPR budgeting.
//  r20: raise LDS above 81920B (28KB pad, DCE-guarded) so only 1 block/CU
//       fits -> LDS-derived target = 16 waves/CU = 4 waves/EU -> 128 VGPR.
//       We already run 1 block/CU (grid=16), so the pad costs nothing.
//       Keep waves_per_eu(4,4) + unroll 8.
//  Kept from r18: S6->S0 barrier merge (6 barriers/step), x_{t+1} reg prefetch.
//  Tripwires: VGPR_Count>64 AND WRITE_SIZE~2.9MB = success. VGPR=64 ->
//       allocator immovable, revert to exact r17 next round and close line.

struct Args {
  const float *x_data, *x_time;
  const float *Wu1, *bu1, *Wu2, *bu2;
  const float *Wr1, *br1, *Wr2, *br2;
  const float *Wn1, *bn1, *Wn2, *bn2;
  const float *Wo1, *bo1, *Wo2, *bo2;
  const float *Wt1, *bt1, *Wt2, *bt2, *Wt3, *bt3;
  float* out;      // f32 output: mu[256*512] then sigma[256*512]
  half_t* wsw;     // swizzled weights (f16)
  float* dts;      // 200 per-step dt values
};

// hw-instruction activations (validated r12/r13: VALU -70%, absmax unchanged)
__device__ __forceinline__ float fast_sigm(float x) {
  return __builtin_amdgcn_rcpf(1.0f + __builtin_amdgcn_exp2f(-LOG2E * x));
}
__device__ __forceinline__ float fast_tanh(float x) {
  return 1.0f - 2.0f * __builtin_amdgcn_rcpf(1.0f + __builtin_amdgcn_exp2f((2.0f * LOG2E) * x));
}

// One 16x16 output tile, K = KB*32. A from LDS, B from pre-swizzled global.
// unroll 8 under the 128-VGPR budget (LDS-pad-forced 1 block/CU target).
template <int KB>
__device__ __forceinline__ f32x4 gemm_tile(const half_t* __restrict__ wtile,
                                           const half_t* __restrict__ abase,
                                           int astride, int lane, f32x4 acc) {
  const half_t* ap = abase + (lane & 15) * astride + 8 * (lane >> 4);
  const half_t* wp = wtile + lane * 8;
#pragma unroll 8
  for (int kb = 0; kb < KB; ++kb) {
    half8 af = *(const half8*)(ap + kb * 32);
    half8 bf = *(const half8*)(wp + kb * 512);
    acc = __builtin_amdgcn_mfma_f32_16x16x32_f16(af, bf, acc, 0, 0, 0);
  }
  return acc;
}

// Pre-swizzle f32 weights into f16 MFMA B-fragment layout, K padded to mult of
// 32 (zeros), N padded to mult of 16 (zeros).
__global__ void swz_kernel(Args a) {
  struct WT { const float* src; int off; int KB; int Kr; int Nr; };
  const WT tbl[11] = {
      {a.Wo1, OFF_WO1, 16, 512, 100},  {a.Wo2, OFF_WO2, 4, 100, 512},
      {a.Wu1, OFF_WU1, 36, 1152, 100}, {a.Wr1, OFF_WR1, 36, 1152, 100},
      {a.Wn1, OFF_WN1, 36, 1152, 100}, {a.Wu2, OFF_WU2, 4, 100, 512},
      {a.Wr2, OFF_WR2, 4, 100, 512},   {a.Wn2, OFF_WN2, 4, 100, 1024},
      {a.Wt1, OFF_WT1, 32, 1024, 100}, {a.Wt2, OFF_WT2, 4, 100, 100},
      {a.Wt3, OFF_WT3, 4, 100, 1024}};
  const int ends[11] = {OFF_WO2, OFF_WU1, OFF_WR1, OFF_WN1, OFF_WU2, OFF_WR2,
                        OFF_WN2, OFF_WT1, OFF_WT2, OFF_WT3, SWZ_TOTAL};
  int gid = blockIdx.x * blockDim.x + threadIdx.x;
  int e8 = gid * 8;
  if (e8 >= SWZ_TOTAL) return;
  int w = 0;
  while (e8 >= ends[w]) ++w;
  const WT T = tbl[w];
  int local = e8 - T.off;
  int lane = (local >> 3) & 63;
  int blk = local >> 9;  // nt*KB + kb
  int kb = blk % T.KB, nt = blk / T.KB;
  int n = nt * 16 + (lane & 15);
  int k0 = kb * 32 + 8 * (lane >> 4);
#pragma unroll
  for (int j = 0; j < 8; ++j) {
    int k = k0 + j;
    float v = (k < T.Kr && n < T.Nr) ? T.src[k * T.Nr + n] : 0.0f;
    a.wsw[e8 + j] = (half_t)v;
  }
}

__global__ void dts_kernel(Args a) {
  int t = threadIdx.x;
  if (t >= T_) return;
  float v;
  if (t == 0)      v = -0.01f;
  else if (t == 1) v = a.x_time[T_ - 1] - a.x_time[0];
  else             v = a.x_time[t - 2] - a.x_time[t - 1];
  a.dts[t] = v;
}

// Persistent ODE-GRU scan: 16 blocks x 1024 threads; block b owns batch rows
// [16b,16b+16). State in registers at C-fragment positions:
//   hreg[s*4+i] = h[m=g*4+i][n=(wave+s*16)*16+lm]  (s=0,1)
// LDS pad forces 1 block/CU so the backend's LDS-derived occupancy target is
// 4 waves/EU -> 128-VGPR budget (r19's attribute alone didn't move it).
__global__ __launch_bounds__(1024)
__attribute__((amdgpu_waves_per_eu(4, 4)))
void odegru_kernel(Args a) {
  // yc stride 1160 f16 (=580 dw == 4 mod 32 -> 2-way-free LDS banks)
  __shared__ __align__(16) half_t yc[16 * 1160];   // [h_ode | hs | x] then c
  __shared__ __align__(16) half_t tg[16 * 136];
  __shared__ __align__(16) half_t tu[16 * 136];
  __shared__ __align__(16) half_t tr[16 * 136];
  __shared__ __align__(16) half_t tn[16 * 136];
  __shared__ float dts_s[T_];
  // occupancy pad: pushes LDS to ~84KB so only 1 block/CU fits (we launch 16
  // blocks on 256 CUs anyway). DCE-guarded by an opaque runtime condition.
  __shared__ half_t lds_pad[14336];

  const int tid = threadIdx.x;
  const int wave = tid >> 6;
  const int lane = tid & 63;
  const int lm = lane & 15;
  const int g = lane >> 4;
  const int row0 = blockIdx.x * 16;

  for (int i = tid; i < 16 * 136; i += 1024) {
    tg[i] = (half_t)0.f; tu[i] = (half_t)0.f; tr[i] = (half_t)0.f; tn[i] = (half_t)0.f;
  }
  if (tid < T_) dts_s[tid] = a.dts[tid];

  // x_t register prefetch: thread covers (xm, xk) and (xm+8, xk); 2048 elems.
  const int xm = tid >> 7, xk = tid & 127;
  const float* xb0 = a.x_data + (long)(row0 + xm) * T_ * X_ + xk;
  const float* xb1 = xb0 + (long)8 * T_ * X_;
  float xp0 = xb0[0];  // t = 0
  float xp1 = xb1[0];

  float hreg[8], hsreg[8];
#pragma unroll
  for (int i = 0; i < 8; ++i) { hreg[i] = 0.f; hsreg[i] = 0.f; }
  float ureg[8];  // u gate: producer wave == consumer wave
  __syncthreads();
  // opaque guard: dts values are runtime data; never true, defeats DCE of pad
  if (dts_s[0] > 1.0e30f) lds_pad[tid] = (half_t)0.f;

  for (int t = 0; t < T_; ++t) {
    const float dt = dts_s[t];
    // ---- S0: yc = [f16(h) | f16(hs) | f16(x_t)] (merged with S6 tail:
    //          no barrier between S6 and S0 — S6 reads tn/regs, S0 writes yc)
#pragma unroll
    for (int s = 0; s < 2; ++s) {
      int n = (wave + s * 16) * 16 + lm;
#pragma unroll
      for (int i = 0; i < 4; ++i) {
        int m = g * 4 + i;
        yc[m * 1160 + n]       = (half_t)hreg[s * 4 + i];
        yc[m * 1160 + 512 + n] = (half_t)hsreg[s * 4 + i];
      }
    }
    yc[xm * 1160 + 1024 + xk]       = (half_t)xp0;
    yc[(xm + 8) * 1160 + 1024 + xk] = (half_t)xp1;
    // prefetch x_{t+1}: latency hides under S1..S6 of this step
    if (t + 1 < T_) {
      xp0 = xb0[(t + 1) * X_];
      xp1 = xb1[(t + 1) * X_];
    }
    __syncthreads();
    // ---- S1: tg = tanh(h @ Wo1 + bo1) ----
    for (int nt = wave; nt < 7; nt += 16) {
      f32x4 acc = {0.f, 0.f, 0.f, 0.f};
      acc = gemm_tile<16>(a.wsw + OFF_WO1 + nt * 16 * 512, yc, 1160, lane, acc);
      int n = nt * 16 + lm;
      if (n < 100) {
        float bias = a.bo1[n];
#pragma unroll
        for (int i = 0; i < 4; ++i)
          tg[(g * 4 + i) * 136 + n] = (half_t)fast_tanh(acc[i] + bias);
      }
    }
    __syncthreads();
    // ---- S2: h_ode = h + dt*(tg @ Wo2 + bo2); hreg := h_ode; yc := f16(h_ode) ----
#pragma unroll
    for (int s = 0; s < 2; ++s) {
      int nt = wave + s * 16;
      f32x4 acc = {0.f, 0.f, 0.f, 0.f};
      acc = gemm_tile<4>(a.wsw + OFF_WO2 + nt * 4 * 512, tg, 136, lane, acc);
      int n = nt * 16 + lm;
      float bias = a.bo2[n];
#pragma unroll
      for (int i = 0; i < 4; ++i) {
        int m = g * 4 + i;
        float h_ode = hreg[s * 4 + i] + dt * (acc[i] + bias);
        hreg[s * 4 + i] = h_ode;
        yc[m * 1160 + n] = (half_t)h_ode;
      }
    }
    __syncthreads();
    // ---- S3: tu = tanh(yc@Wu1+bu1), tr = tanh(yc@Wr1+br1) (14 tiles) ----
    for (int nt = wave; nt < 14; nt += 16) {
      bool isU = nt < 7;
      int nt7 = isU ? nt : nt - 7;
      f32x4 acc = {0.f, 0.f, 0.f, 0.f};
      acc = gemm_tile<36>(a.wsw + (isU ? OFF_WU1 : OFF_WR1) + nt7 * 36 * 512, yc, 1160, lane, acc);
      int n = nt7 * 16 + lm;
      if (n < 100) {
        float bias = (isU ? a.bu1 : a.br1)[n];
        half_t* dst = isU ? tu : tr;
#pragma unroll
        for (int i = 0; i < 4; ++i)
          dst[(g * 4 + i) * 136 + n] = (half_t)fast_tanh(acc[i] + bias);
      }
    }
    __syncthreads();
    // ---- S4: u -> ureg ; r -> fused c-build into yc ----
#pragma unroll
    for (int s = 0; s < 2; ++s) {
      int nt = wave + s * 16;
      f32x4 acc = {0.f, 0.f, 0.f, 0.f};
      acc = gemm_tile<4>(a.wsw + OFF_WU2 + nt * 4 * 512, tu, 136, lane, acc);
      int n = nt * 16 + lm;
      float bias = a.bu2[n];
#pragma unroll
      for (int i = 0; i < 4; ++i) ureg[s * 4 + i] = fast_sigm(acc[i] + bias);
    }
#pragma unroll
    for (int s = 0; s < 2; ++s) {
      int nt = wave + s * 16;
      f32x4 acc = {0.f, 0.f, 0.f, 0.f};
      acc = gemm_tile<4>(a.wsw + OFF_WR2 + nt * 4 * 512, tr, 136, lane, acc);
      int n = nt * 16 + lm;
      float bias = a.br2[n];
#pragma unroll
      for (int i = 0; i < 4; ++i) {
        int m = g * 4 + i;
        float r = fast_sigm(acc[i] + bias);
        yc[m * 1160 + n]       = (half_t)(hreg[s * 4 + i] * r);
        yc[m * 1160 + 512 + n] = (half_t)(hsreg[s * 4 + i] * r);
      }
    }
    __syncthreads();
    // ---- S5: tn = tanh(c @ Wn1 + bn1) ----
    for (int nt = wave; nt < 7; nt += 16) {
      f32x4 acc = {0.f, 0.f, 0.f, 0.f};
      acc = gemm_tile<36>(a.wsw + OFF_WN1 + nt * 36 * 512, yc, 1160, lane, acc);
      int n = nt * 16 + lm;
      if (n < 100) {
        float bias = a.bn1[n];
#pragma unroll
        for (int i = 0; i < 4; ++i)
          tn[(g * 4 + i) * 136 + n] = (half_t)fast_tanh(acc[i] + bias);
      }
    }
    __syncthreads();
    // ---- S6: ns = tn @ Wn2 + bn2; gated state update in registers ----
    //      (no trailing barrier: merged with next step's S0)
#pragma unroll
    for (int s = 0; s < 4; ++s) {
      int nt = wave + s * 16;
      f32x4 acc = {0.f, 0.f, 0.f, 0.f};
      acc = gemm_tile<4>(a.wsw + OFF_WN2 + nt * 4 * 512, tn, 136, lane, acc);
      int n = nt * 16 + lm;
      float bias = a.bn2[n];
      if (s < 2) {  // m-part -> h update
#pragma unroll
        for (int i = 0; i < 4; ++i) {
          float u = ureg[s * 4 + i];
          float mval = acc[i] + bias;
          hreg[s * 4 + i] = (1.0f - u) * mval + u * hreg[s * 4 + i];
        }
      } else {      // s-part -> hs update (same n-tile as ureg[s-2])
#pragma unroll
        for (int i = 0; i < 4; ++i) {
          float u = ureg[(s - 2) * 4 + i];
          float sval = fabsf(acc[i] + bias);
          hsreg[(s - 2) * 4 + i] = (1.0f - u) * sval + u * hsreg[(s - 2) * 4 + i];
        }
      }
    }
  }

  // ---- Final decoder ----
#pragma unroll
  for (int s = 0; s < 2; ++s) {
    int n = (wave + s * 16) * 16 + lm;
#pragma unroll
    for (int i = 0; i < 4; ++i) {
      int m = g * 4 + i;
      yc[m * 1160 + n]       = (half_t)hreg[s * 4 + i];
      yc[m * 1160 + 512 + n] = (half_t)hsreg[s * 4 + i];
    }
  }
  __syncthreads();
  for (int nt = wave; nt < 7; nt += 16) {  // z1 = tanh(hcat@Wt1+bt1)
    f32x4 acc = {0.f, 0.f, 0.f, 0.f};
    acc = gemm_tile<32>(a.wsw + OFF_WT1 + nt * 32 * 512, yc, 1160, lane, acc);
    int n = nt * 16 + lm;
    if (n < 100) {
      float bias = a.bt1[n];
#pragma unroll
      for (int i = 0; i < 4; ++i)
        tu[(g * 4 + i) * 136 + n] = (half_t)fast_tanh(acc[i] + bias);
    }
  }
  __syncthreads();
  for (int nt = wave; nt < 7; nt += 16) {  // z2 = tanh(z1@Wt2+bt2)
    f32x4 acc = {0.f, 0.f, 0.f, 0.f};
    acc = gemm_tile<4>(a.wsw + OFF_WT2 + nt * 4 * 512, tu, 136, lane, acc);
    int n = nt * 16 + lm;
    if (n < 100) {
      float bias = a.bt2[n];
#pragma unroll
      for (int i = 0; i < 4; ++i)
        tr[(g * 4 + i) * 136 + n] = (half_t)fast_tanh(acc[i] + bias);
    }
  }
  __syncthreads();
#pragma unroll
  for (int s = 0; s < 4; ++s) {  // z3 = z2@Wt3+bt3 -> mu | sigma (f32 out)
    int nt = wave + s * 16;
    f32x4 acc = {0.f, 0.f, 0.f, 0.f};
    acc = gemm_tile<4>(a.wsw + OFF_WT3 + nt * 4 * 512, tr, 136, lane, acc);
    int n = nt * 16 + lm;
    float bias = a.bt3[n];
#pragma unroll
    for (int i = 0; i < 4; ++i) {
      int grow = row0 + g * 4 + i;
      float val = acc[i] + bias;
      if (n < 512)
        a.out[(size_t)grow * 512 + n] = val;
      else
        a.out[(size_t)(B_ * 512) + (size_t)grow * 512 + (n - 512)] = fabsf(val);
    }
  }
}

extern "C" void kernel_launch(void* const* d_in, const int* in_sizes, int n_in,
                              void* d_out, int out_size, void* d_ws, size_t ws_size,
                              hipStream_t stream) {
  Args a;
  a.x_data = (const float*)d_in[0];
  a.x_time = (const float*)d_in[1];
  a.Wu1 = (const float*)d_in[2];  a.bu1 = (const float*)d_in[3];
  a.Wu2 = (const float*)d_in[4];  a.bu2 = (const float*)d_in[5];
  a.Wr1 = (const float*)d_in[6];  a.br1 = (const float*)d_in[7];
  a.Wr2 = (const float*)d_in[8];  a.br2 = (const float*)d_in[9];
  a.Wn1 = (const float*)d_in[10]; a.bn1 = (const float*)d_in[11];
  a.Wn2 = (const float*)d_in[12]; a.bn2 = (const float*)d_in[13];
  a.Wo1 = (const float*)d_in[14]; a.bo1 = (const float*)d_in[15];
  a.Wo2 = (const float*)d_in[16]; a.bo2 = (const float*)d_in[17];
  a.Wt1 = (const float*)d_in[18]; a.bt1 = (const float*)d_in[19];
  a.Wt2 = (const float*)d_in[20]; a.bt2 = (const float*)d_in[21];
  a.Wt3 = (const float*)d_in[22]; a.bt3 = (const float*)d_in[23];
  a.out = (float*)d_out;
  a.wsw = (half_t*)d_ws;
  a.dts = (float*)((char*)d_ws + DTS_BYTE_OFF);

  swz_kernel<<<dim3(504), dim3(256), 0, stream>>>(a);
  dts_kernel<<<dim3(1), dim3(256), 0, stream>>>(a);
  odegru_kernel<<<dim3(16), dim3(1024), 0, stream>>>(a);
}

// Round 4
// 3601.455 us; speedup vs baseline: 1.5075x; 1.5036x over previous
//
#include <hip/hip_runtime.h>

typedef unsigned short ushort_t;
typedef _Float16 half_t;
typedef __attribute__((ext_vector_type(8))) _Float16 half8;
typedef __attribute__((ext_vector_type(4))) float f32x4;

#define B_ 256
#define T_ 200
#define X_ 128
#define H_ 512

// swizzled weight offsets in d_ws (f16 elements)
#define OFF_WO1 0
#define OFF_WO2 57344
#define OFF_WU1 122880
#define OFF_WR1 251904
#define OFF_WN1 380928
#define OFF_WU2 509952
#define OFF_WR2 575488
#define OFF_WN2 641024
#define OFF_WT1 772096
#define OFF_WT2 886784
#define OFF_WT3 901120
#define SWZ_TOTAL 1032192
#define DTS_BYTE_OFF (SWZ_TOTAL * 2)

#define LOG2E 1.4426950408889634f

// ===== r21 = r17 structure + two zero/low-cost latency fixes. Ledger: =====
//  r12/r14: unroll>4 at 64-VGPR cap -> spill. r15: split-K -> +8.5%. CLOSED.
//  r16: x-part hoist -> +5%. CLOSED.
//  r18: launch_bounds(1024,4): VGPR budget unmoved -> unroll-8 spill, 5380us.
//  r19: amdgpu_waves_per_eu(4,4): SGPR moved (48->112), VGPR didn't -> 5429us.
//  r20: 28KB LDS pad to force 1 block/CU: pad DCE'd (never-read store),
//       LDS_Block_Size stayed 55808 -> 5415us. VGPR budget is immovable at
//       source level on this ROCm. DEEP-UNROLL LINE CLOSED. unroll stays 4.
//  r21a (= r18a, kept): S6->S0 barrier merge. S6 reads tn + registers only;
//       S5's yc reads are fenced from S0's yc writes by the S5->S6 barrier.
//       7 -> 6 barriers/step, zero register cost.
//  r21b (r18b FIXED): x_{t+1} prefetch issued AFTER the S0 barrier. r18b
//       issued it before __syncthreads, whose vmcnt(0) drain killed the
//       overlap. Now the load drains at the end-of-S1 barrier, hiding the
//       ~900cy HBM miss under S1's 7-tile MFMA work (~100-130us total).
//  Tripwire: WRITE_SIZE must return to ~2.9MB. >4MB = xp regs spilled ->
//       revert to exact r17 next round.

struct Args {
  const float *x_data, *x_time;
  const float *Wu1, *bu1, *Wu2, *bu2;
  const float *Wr1, *br1, *Wr2, *br2;
  const float *Wn1, *bn1, *Wn2, *bn2;
  const float *Wo1, *bo1, *Wo2, *bo2;
  const float *Wt1, *bt1, *Wt2, *bt2, *Wt3, *bt3;
  float* out;      // f32 output: mu[256*512] then sigma[256*512]
  half_t* wsw;     // swizzled weights (f16)
  float* dts;      // 200 per-step dt values
};

// hw-instruction activations (validated r12/r13: VALU -70%, absmax unchanged)
__device__ __forceinline__ float fast_sigm(float x) {
  return __builtin_amdgcn_rcpf(1.0f + __builtin_amdgcn_exp2f(-LOG2E * x));
}
__device__ __forceinline__ float fast_tanh(float x) {
  return 1.0f - 2.0f * __builtin_amdgcn_rcpf(1.0f + __builtin_amdgcn_exp2f((2.0f * LOG2E) * x));
}

// One 16x16 output tile, K = KB*32. A from LDS, B from pre-swizzled global.
// Keep "#pragma unroll 4" (deep unroll closed: r12/r18/r19/r20 all spill).
template <int KB>
__device__ __forceinline__ f32x4 gemm_tile(const half_t* __restrict__ wtile,
                                           const half_t* __restrict__ abase,
                                           int astride, int lane, f32x4 acc) {
  const half_t* ap = abase + (lane & 15) * astride + 8 * (lane >> 4);
  const half_t* wp = wtile + lane * 8;
#pragma unroll 4
  for (int kb = 0; kb < KB; ++kb) {
    half8 af = *(const half8*)(ap + kb * 32);
    half8 bf = *(const half8*)(wp + kb * 512);
    acc = __builtin_amdgcn_mfma_f32_16x16x32_f16(af, bf, acc, 0, 0, 0);
  }
  return acc;
}

// Pre-swizzle f32 weights into f16 MFMA B-fragment layout, K padded to mult of
// 32 (zeros), N padded to mult of 16 (zeros).
__global__ void swz_kernel(Args a) {
  struct WT { const float* src; int off; int KB; int Kr; int Nr; };
  const WT tbl[11] = {
      {a.Wo1, OFF_WO1, 16, 512, 100},  {a.Wo2, OFF_WO2, 4, 100, 512},
      {a.Wu1, OFF_WU1, 36, 1152, 100}, {a.Wr1, OFF_WR1, 36, 1152, 100},
      {a.Wn1, OFF_WN1, 36, 1152, 100}, {a.Wu2, OFF_WU2, 4, 100, 512},
      {a.Wr2, OFF_WR2, 4, 100, 512},   {a.Wn2, OFF_WN2, 4, 100, 1024},
      {a.Wt1, OFF_WT1, 32, 1024, 100}, {a.Wt2, OFF_WT2, 4, 100, 100},
      {a.Wt3, OFF_WT3, 4, 100, 1024}};
  const int ends[11] = {OFF_WO2, OFF_WU1, OFF_WR1, OFF_WN1, OFF_WU2, OFF_WR2,
                        OFF_WN2, OFF_WT1, OFF_WT2, OFF_WT3, SWZ_TOTAL};
  int gid = blockIdx.x * blockDim.x + threadIdx.x;
  int e8 = gid * 8;
  if (e8 >= SWZ_TOTAL) return;
  int w = 0;
  while (e8 >= ends[w]) ++w;
  const WT T = tbl[w];
  int local = e8 - T.off;
  int lane = (local >> 3) & 63;
  int blk = local >> 9;  // nt*KB + kb
  int kb = blk % T.KB, nt = blk / T.KB;
  int n = nt * 16 + (lane & 15);
  int k0 = kb * 32 + 8 * (lane >> 4);
#pragma unroll
  for (int j = 0; j < 8; ++j) {
    int k = k0 + j;
    float v = (k < T.Kr && n < T.Nr) ? T.src[k * T.Nr + n] : 0.0f;
    a.wsw[e8 + j] = (half_t)v;
  }
}

__global__ void dts_kernel(Args a) {
  int t = threadIdx.x;
  if (t >= T_) return;
  float v;
  if (t == 0)      v = -0.01f;
  else if (t == 1) v = a.x_time[T_ - 1] - a.x_time[0];
  else             v = a.x_time[t - 2] - a.x_time[t - 1];
  a.dts[t] = v;
}

// Persistent ODE-GRU scan: 16 blocks x 1024 threads; block b owns batch rows
// [16b,16b+16). State in registers at C-fragment positions:
//   hreg[s*4+i] = h[m=g*4+i][n=(wave+s*16)*16+lm]  (s=0,1)
__global__ __launch_bounds__(1024) void odegru_kernel(Args a) {
  // yc stride 1160 f16 (=580 dw == 4 mod 32 -> 2-way-free LDS banks)
  __shared__ __align__(16) half_t yc[16 * 1160];   // [h_ode | hs | x] then c
  __shared__ __align__(16) half_t tg[16 * 136];
  __shared__ __align__(16) half_t tu[16 * 136];
  __shared__ __align__(16) half_t tr[16 * 136];
  __shared__ __align__(16) half_t tn[16 * 136];
  __shared__ float dts_s[T_];

  const int tid = threadIdx.x;
  const int wave = tid >> 6;
  const int lane = tid & 63;
  const int lm = lane & 15;
  const int g = lane >> 4;
  const int row0 = blockIdx.x * 16;

  for (int i = tid; i < 16 * 136; i += 1024) {
    tg[i] = (half_t)0.f; tu[i] = (half_t)0.f; tr[i] = (half_t)0.f; tn[i] = (half_t)0.f;
  }
  if (tid < T_) dts_s[tid] = a.dts[tid];

  // x prefetch: thread covers (xm, xk) and (xm+8, xk); 2048 elems per step.
  const int xm = tid >> 7, xk = tid & 127;
  const float* xb0 = a.x_data + (long)(row0 + xm) * T_ * X_ + xk;
  const float* xb1 = xb0 + (long)8 * T_ * X_;
  float xp0 = xb0[0];  // t = 0 (exposed once, before the loop)
  float xp1 = xb1[0];

  float hreg[8], hsreg[8];
#pragma unroll
  for (int i = 0; i < 8; ++i) { hreg[i] = 0.f; hsreg[i] = 0.f; }
  float ureg[8];  // u gate: producer wave == consumer wave
  __syncthreads();

  for (int t = 0; t < T_; ++t) {
    const float dt = dts_s[t];
    // ---- S0: yc = [f16(h) | f16(hs) | f16(x_t)] (merged with S6 tail:
    //          no barrier between S6 and S0 — S6 reads tn/regs, S0 writes yc;
    //          S5's yc reads are fenced by the S5->S6 barrier)
#pragma unroll
    for (int s = 0; s < 2; ++s) {
      int n = (wave + s * 16) * 16 + lm;
#pragma unroll
      for (int i = 0; i < 4; ++i) {
        int m = g * 4 + i;
        yc[m * 1160 + n]       = (half_t)hreg[s * 4 + i];
        yc[m * 1160 + 512 + n] = (half_t)hsreg[s * 4 + i];
      }
    }
    yc[xm * 1160 + 1024 + xk]       = (half_t)xp0;
    yc[(xm + 8) * 1160 + 1024 + xk] = (half_t)xp1;
    __syncthreads();
    // x_{t+1} prefetch issued AFTER the barrier: drains at the end-of-S1
    // barrier, i.e. the HBM miss hides under S1's MFMA work. (Issuing before
    // the barrier — r18b — was useless: __syncthreads' vmcnt(0) drained it.)
    if (t + 1 < T_) {
      xp0 = xb0[(t + 1) * X_];
      xp1 = xb1[(t + 1) * X_];
    }
    // ---- S1: tg = tanh(h @ Wo1 + bo1) ----
    for (int nt = wave; nt < 7; nt += 16) {
      f32x4 acc = {0.f, 0.f, 0.f, 0.f};
      acc = gemm_tile<16>(a.wsw + OFF_WO1 + nt * 16 * 512, yc, 1160, lane, acc);
      int n = nt * 16 + lm;
      if (n < 100) {
        float bias = a.bo1[n];
#pragma unroll
        for (int i = 0; i < 4; ++i)
          tg[(g * 4 + i) * 136 + n] = (half_t)fast_tanh(acc[i] + bias);
      }
    }
    __syncthreads();
    // ---- S2: h_ode = h + dt*(tg @ Wo2 + bo2); hreg := h_ode; yc := f16(h_ode) ----
#pragma unroll
    for (int s = 0; s < 2; ++s) {
      int nt = wave + s * 16;
      f32x4 acc = {0.f, 0.f, 0.f, 0.f};
      acc = gemm_tile<4>(a.wsw + OFF_WO2 + nt * 4 * 512, tg, 136, lane, acc);
      int n = nt * 16 + lm;
      float bias = a.bo2[n];
#pragma unroll
      for (int i = 0; i < 4; ++i) {
        int m = g * 4 + i;
        float h_ode = hreg[s * 4 + i] + dt * (acc[i] + bias);
        hreg[s * 4 + i] = h_ode;
        yc[m * 1160 + n] = (half_t)h_ode;
      }
    }
    __syncthreads();
    // ---- S3: tu = tanh(yc@Wu1+bu1), tr = tanh(yc@Wr1+br1) (14 tiles) ----
    for (int nt = wave; nt < 14; nt += 16) {
      bool isU = nt < 7;
      int nt7 = isU ? nt : nt - 7;
      f32x4 acc = {0.f, 0.f, 0.f, 0.f};
      acc = gemm_tile<36>(a.wsw + (isU ? OFF_WU1 : OFF_WR1) + nt7 * 36 * 512, yc, 1160, lane, acc);
      int n = nt7 * 16 + lm;
      if (n < 100) {
        float bias = (isU ? a.bu1 : a.br1)[n];
        half_t* dst = isU ? tu : tr;
#pragma unroll
        for (int i = 0; i < 4; ++i)
          dst[(g * 4 + i) * 136 + n] = (half_t)fast_tanh(acc[i] + bias);
      }
    }
    __syncthreads();
    // ---- S4: u -> ureg ; r -> fused c-build into yc ----
#pragma unroll
    for (int s = 0; s < 2; ++s) {
      int nt = wave + s * 16;
      f32x4 acc = {0.f, 0.f, 0.f, 0.f};
      acc = gemm_tile<4>(a.wsw + OFF_WU2 + nt * 4 * 512, tu, 136, lane, acc);
      int n = nt * 16 + lm;
      float bias = a.bu2[n];
#pragma unroll
      for (int i = 0; i < 4; ++i) ureg[s * 4 + i] = fast_sigm(acc[i] + bias);
    }
#pragma unroll
    for (int s = 0; s < 2; ++s) {
      int nt = wave + s * 16;
      f32x4 acc = {0.f, 0.f, 0.f, 0.f};
      acc = gemm_tile<4>(a.wsw + OFF_WR2 + nt * 4 * 512, tr, 136, lane, acc);
      int n = nt * 16 + lm;
      float bias = a.br2[n];
#pragma unroll
      for (int i = 0; i < 4; ++i) {
        int m = g * 4 + i;
        float r = fast_sigm(acc[i] + bias);
        yc[m * 1160 + n]       = (half_t)(hreg[s * 4 + i] * r);
        yc[m * 1160 + 512 + n] = (half_t)(hsreg[s * 4 + i] * r);
      }
    }
    __syncthreads();
    // ---- S5: tn = tanh(c @ Wn1 + bn1) ----
    for (int nt = wave; nt < 7; nt += 16) {
      f32x4 acc = {0.f, 0.f, 0.f, 0.f};
      acc = gemm_tile<36>(a.wsw + OFF_WN1 + nt * 36 * 512, yc, 1160, lane, acc);
      int n = nt * 16 + lm;
      if (n < 100) {
        float bias = a.bn1[n];
#pragma unroll
        for (int i = 0; i < 4; ++i)
          tn[(g * 4 + i) * 136 + n] = (half_t)fast_tanh(acc[i] + bias);
      }
    }
    __syncthreads();
    // ---- S6: ns = tn @ Wn2 + bn2; gated state update in registers ----
    //      (no trailing barrier: merged with next step's S0)
#pragma unroll
    for (int s = 0; s < 4; ++s) {
      int nt = wave + s * 16;
      f32x4 acc = {0.f, 0.f, 0.f, 0.f};
      acc = gemm_tile<4>(a.wsw + OFF_WN2 + nt * 4 * 512, tn, 136, lane, acc);
      int n = nt * 16 + lm;
      float bias = a.bn2[n];
      if (s < 2) {  // m-part -> h update
#pragma unroll
        for (int i = 0; i < 4; ++i) {
          float u = ureg[s * 4 + i];
          float mval = acc[i] + bias;
          hreg[s * 4 + i] = (1.0f - u) * mval + u * hreg[s * 4 + i];
        }
      } else {      // s-part -> hs update (same n-tile as ureg[s-2])
#pragma unroll
        for (int i = 0; i < 4; ++i) {
          float u = ureg[(s - 2) * 4 + i];
          float sval = fabsf(acc[i] + bias);
          hsreg[(s - 2) * 4 + i] = (1.0f - u) * sval + u * hsreg[(s - 2) * 4 + i];
        }
      }
    }
  }

  // ---- Final decoder ----
#pragma unroll
  for (int s = 0; s < 2; ++s) {
    int n = (wave + s * 16) * 16 + lm;
#pragma unroll
    for (int i = 0; i < 4; ++i) {
      int m = g * 4 + i;
      yc[m * 1160 + n]       = (half_t)hreg[s * 4 + i];
      yc[m * 1160 + 512 + n] = (half_t)hsreg[s * 4 + i];
    }
  }
  __syncthreads();
  for (int nt = wave; nt < 7; nt += 16) {  // z1 = tanh(hcat@Wt1+bt1)
    f32x4 acc = {0.f, 0.f, 0.f, 0.f};
    acc = gemm_tile<32>(a.wsw + OFF_WT1 + nt * 32 * 512, yc, 1160, lane, acc);
    int n = nt * 16 + lm;
    if (n < 100) {
      float bias = a.bt1[n];
#pragma unroll
      for (int i = 0; i < 4; ++i)
        tu[(g * 4 + i) * 136 + n] = (half_t)fast_tanh(acc[i] + bias);
    }
  }
  __syncthreads();
  for (int nt = wave; nt < 7; nt += 16) {  // z2 = tanh(z1@Wt2+bt2)
    f32x4 acc = {0.f, 0.f, 0.f, 0.f};
    acc = gemm_tile<4>(a.wsw + OFF_WT2 + nt * 4 * 512, tu, 136, lane, acc);
    int n = nt * 16 + lm;
    if (n < 100) {
      float bias = a.bt2[n];
#pragma unroll
      for (int i = 0; i < 4; ++i)
        tr[(g * 4 + i) * 136 + n] = (half_t)fast_tanh(acc[i] + bias);
    }
  }
  __syncthreads();
#pragma unroll
  for (int s = 0; s < 4; ++s) {  // z3 = z2@Wt3+bt3 -> mu | sigma (f32 out)
    int nt = wave + s * 16;
    f32x4 acc = {0.f, 0.f, 0.f, 0.f};
    acc = gemm_tile<4>(a.wsw + OFF_WT3 + nt * 4 * 512, tr, 136, lane, acc);
    int n = nt * 16 + lm;
    float bias = a.bt3[n];
#pragma unroll
    for (int i = 0; i < 4; ++i) {
      int grow = row0 + g * 4 + i;
      float val = acc[i] + bias;
      if (n < 512)
        a.out[(size_t)grow * 512 + n] = val;
      else
        a.out[(size_t)(B_ * 512) + (size_t)grow * 512 + (n - 512)] = fabsf(val);
    }
  }
}

extern "C" void kernel_launch(void* const* d_in, const int* in_sizes, int n_in,
                              void* d_out, int out_size, void* d_ws, size_t ws_size,
                              hipStream_t stream) {
  Args a;
  a.x_data = (const float*)d_in[0];
  a.x_time = (const float*)d_in[1];
  a.Wu1 = (const float*)d_in[2];  a.bu1 = (const float*)d_in[3];
  a.Wu2 = (const float*)d_in[4];  a.bu2 = (const float*)d_in[5];
  a.Wr1 = (const float*)d_in[6];  a.br1 = (const float*)d_in[7];
  a.Wr2 = (const float*)d_in[8];  a.br2 = (const float*)d_in[9];
  a.Wn1 = (const float*)d_in[10]; a.bn1 = (const float*)d_in[11];
  a.Wn2 = (const float*)d_in[12]; a.bn2 = (const float*)d_in[13];
  a.Wo1 = (const float*)d_in[14]; a.bo1 = (const float*)d_in[15];
  a.Wo2 = (const float*)d_in[16]; a.bo2 = (const float*)d_in[17];
  a.Wt1 = (const float*)d_in[18]; a.bt1 = (const float*)d_in[19];
  a.Wt2 = (const float*)d_in[20]; a.bt2 = (const float*)d_in[21];
  a.Wt3 = (const float*)d_in[22]; a.bt3 = (const float*)d_in[23];
  a.out = (float*)d_out;
  a.wsw = (half_t*)d_ws;
  a.dts = (float*)((char*)d_ws + DTS_BYTE_OFF);

  swz_kernel<<<dim3(504), dim3(256), 0, stream>>>(a);
  dts_kernel<<<dim3(1), dim3(256), 0, stream>>>(a);
  odegru_kernel<<<dim3(16), dim3(1024), 0, stream>>>(a);
}